// Round 7
// baseline (317.883 us; speedup 1.0000x reference)
//
#include <hip/hip_runtime.h>
#include <hip/hip_bf16.h>

#define NUM_GRAPHS 64
#define NODES 256
#define EDGES 1024
#define NTOT (NUM_GRAPHS * NODES) /* 16384 */
#define DF 512
#define HF 1024
#define HP 256
#define NC 10
#define INF32 0xFFFFFFFFu

typedef short bf16x8 __attribute__((ext_vector_type(8)));
typedef float f32x4 __attribute__((ext_vector_type(4)));

__device__ __forceinline__ unsigned short bf16r(float f) {
    __hip_bfloat16 h = __float2bfloat16(f);
    return *(unsigned short*)&h;
}
// monotone order-preserving encode for fp32 (bijection, works for +/-)
__device__ __forceinline__ unsigned encf(float x) {
    union { float f; unsigned u; } c; c.f = x;
    return (c.u & 0x80000000u) ? ~c.u : (c.u | 0x80000000u);
}

// ---- w1 (f32 [k][j]) -> w1f bf16, LANE-ORDERED MFMA B-fragment layout ----
// Element addr: ((cg*16 + t)*64 + lane)*8 shorts, lane = quad*16 + n16;
// lane holds B[k = t*32 + quad*8 + j][col = cg*16 + n16].
__global__ __launch_bounds__(256) void k_cvt_frag(
    const float* __restrict__ w1, unsigned short* __restrict__ w1f)
{
    __shared__ float ls[128 * 16];   // [kk][c], 8 KB
    const int tid = threadIdx.x;
    const int cg = blockIdx.x >> 2, kq = blockIdx.x & 3;
    const int c = tid & 15, kr = tid >> 4;
#pragma unroll
    for (int it = 0; it < 8; ++it) {
        int kk = it * 16 + kr;
        ls[kk * 16 + c] = w1[(size_t)(kq * 128 + kk) * HF + cg * 16 + c];
    }
    __syncthreads();
    const int tt = tid >> 6, n16 = tid & 15, q = (tid >> 4) & 3;
    unsigned short v[8];
#pragma unroll
    for (int j = 0; j < 8; ++j)
        v[j] = bf16r(ls[(tt * 32 + q * 8 + j) * 16 + n16]);
    size_t off = ((size_t)(cg * 16 + kq * 4 + tt) * 64 + (q * 16 + n16)) * 8;
#pragma unroll
    for (int j = 0; j < 8; ++j) w1f[off + j] = v[j];
}

// ------- Stage 1 (MFMA v6): zbuf = relu(x@W1+b1)@w2 (pre-b2/sigmoid) ------
// 256 blocks x 64 rows x 256 thr. Wave wv: rows r0+(wv&1)*32..+32 (A in 128
// VGPR), cols half (wv>>1)*512..+512 (32 cgs). B quad-buffered 4x16 KB LDS;
// per-step staging of one cg per half. 4 independent MFMA chains. Partial
// sums joined across halves via LDS. Math identical to v5b (K split 2).
__global__ __launch_bounds__(256, 1) void k_fil_mfma(
    const float* __restrict__ x, const unsigned short* __restrict__ w1f,
    const float* __restrict__ b1, const float* __restrict__ w2,
    float* __restrict__ zbuf)
{
    __shared__ unsigned short Bbuf[4 * 16 * 512];  // 4 x 16 KB
    __shared__ float zpart[4][32];
    const int tid = threadIdx.x;
    const int lane = tid & 63;
    const int wv = tid >> 6;            // 0..3
    const int l15 = lane & 15, quad = lane >> 4;
    const int half = wv >> 1;           // column half (32 cgs)
    const int rt = wv & 1;              // row 32-tile
    const int r0 = blockIdx.x * 64;
    const int rowA = r0 + rt * 32 + l15;
    const int rowB = rowA + 16;

    // A fragments for 32 rows: two 16-row tiles, f32 -> bf16 in regs
    bf16x8 A0[16], A1[16];
#pragma unroll
    for (int t = 0; t < 16; ++t) {
        const float* s0 = x + (size_t)rowA * DF + t * 32 + quad * 8;
        const float* s1 = x + (size_t)rowB * DF + t * 32 + quad * 8;
        float4 a = *(const float4*)s0, b = *(const float4*)(s0 + 4);
        float4 c = *(const float4*)s1, d = *(const float4*)(s1 + 4);
        A0[t][0]=(short)bf16r(a.x); A0[t][1]=(short)bf16r(a.y);
        A0[t][2]=(short)bf16r(a.z); A0[t][3]=(short)bf16r(a.w);
        A0[t][4]=(short)bf16r(b.x); A0[t][5]=(short)bf16r(b.y);
        A0[t][6]=(short)bf16r(b.z); A0[t][7]=(short)bf16r(b.w);
        A1[t][0]=(short)bf16r(c.x); A1[t][1]=(short)bf16r(c.y);
        A1[t][2]=(short)bf16r(c.z); A1[t][3]=(short)bf16r(c.w);
        A1[t][4]=(short)bf16r(d.x); A1[t][5]=(short)bf16r(d.y);
        A1[t][6]=(short)bf16r(d.z); A1[t][7]=(short)bf16r(d.w);
    }

    // staging: threads 0-127 stage half 0, 128-255 stage half 1 (8 uint4 ea)
    const int t128 = tid & 127;
    const int sh = tid >> 7;
    uint4 pf[8];
    {
        const uint4* s = (const uint4*)(w1f + (size_t)(sh * 32) * 8192);
#pragma unroll
        for (int j = 0; j < 8; ++j) pf[j] = s[t128 + j * 128];
        uint4* d = (uint4*)Bbuf + (sh * 2 + 0) * 1024;
#pragma unroll
        for (int j = 0; j < 8; ++j) d[t128 + j * 128] = pf[j];
    }
    __syncthreads();

    float s_[2][4] = {{0,0,0,0},{0,0,0,0}};

    for (int i = 0; i < 32; ++i) {
        const int par = i & 1;
        if (i < 31) {
            const uint4* s = (const uint4*)(w1f + (size_t)(sh * 32 + i + 1) * 8192);
#pragma unroll
            for (int j = 0; j < 8; ++j) pf[j] = s[t128 + j * 128];
        }
        const unsigned short* bb = Bbuf + (half * 2 + par) * 8192 + lane * 8;
        f32x4 a00={0,0,0,0}, a01={0,0,0,0}, a10={0,0,0,0}, a11={0,0,0,0};
#pragma unroll
        for (int t = 0; t < 8; ++t) {
            bf16x8 Bf0 = *(const bf16x8*)(bb + t * 512);
            bf16x8 Bf1 = *(const bf16x8*)(bb + (t + 8) * 512);
            a00 = __builtin_amdgcn_mfma_f32_16x16x32_bf16(A0[t], Bf0, a00, 0, 0, 0);
            a10 = __builtin_amdgcn_mfma_f32_16x16x32_bf16(A1[t], Bf0, a10, 0, 0, 0);
            a01 = __builtin_amdgcn_mfma_f32_16x16x32_bf16(A0[t + 8], Bf1, a01, 0, 0, 0);
            a11 = __builtin_amdgcn_mfma_f32_16x16x32_bf16(A1[t + 8], Bf1, a11, 0, 0, 0);
        }
        const int col = (half * 32 + i) * 16 + l15;
        const float b1c = b1[col], w2c = w2[col];
#pragma unroll
        for (int r = 0; r < 4; ++r) {
            float h0 = (a00[r] + a01[r]) + b1c; h0 = h0 > 0.f ? h0 : 0.f;
            s_[0][r] = fmaf(h0, w2c, s_[0][r]);
            float h1 = (a10[r] + a11[r]) + b1c; h1 = h1 > 0.f ? h1 : 0.f;
            s_[1][r] = fmaf(h1, w2c, s_[1][r]);
        }
        if (i < 31) {
            uint4* d = (uint4*)Bbuf + (sh * 2 + (par ^ 1)) * 1024;
#pragma unroll
            for (int j = 0; j < 8; ++j) d[t128 + j * 128] = pf[j];
        }
        __syncthreads();
    }

    // reduce over 16 col-lanes; publish per-wave partials; join halves
#pragma unroll
    for (int sub = 0; sub < 2; ++sub)
#pragma unroll
        for (int r = 0; r < 4; ++r) {
            float v = s_[sub][r];
            v += __shfl_xor(v, 1, 16);
            v += __shfl_xor(v, 2, 16);
            v += __shfl_xor(v, 4, 16);
            v += __shfl_xor(v, 8, 16);
            if (l15 == 0) zpart[wv][sub * 16 + quad * 4 + r] = v;
        }
    __syncthreads();
    if (tid < 64) {
        int rrt = tid >> 5, idx = tid & 31;
        zbuf[r0 + tid] = zpart[rrt][idx] + zpart[rrt + 2][idx];
    }
}

// ---------------- Stage 1 legacy (fp32 VALU) — ws_size fallback -----------
#define TN2 16
__global__ __launch_bounds__(256) void k_fil(
    const float* __restrict__ x, const float* __restrict__ w1,
    const float* __restrict__ b1, const float* __restrict__ w2,
    float* __restrict__ zout)
{
    __shared__ float xs[TN2][DF];
    __shared__ float part[256];
    const int tid = threadIdx.x;
    const int n0 = blockIdx.x * TN2;
    for (int c = tid; c < TN2 * DF / 4; c += 256) {
        int n = c >> 7, k4 = (c & 127) << 2;
        *(float4*)&xs[n][k4] = *(const float4*)(x + (size_t)(n0 + n) * DF + k4);
    }
    __syncthreads();
    float h[TN2][4];
#pragma unroll
    for (int n = 0; n < TN2; ++n)
#pragma unroll
        for (int q = 0; q < 4; ++q) h[n][q] = 0.f;
    for (int k = 0; k < DF; ++k) {
        float wr[4];
#pragma unroll
        for (int q = 0; q < 4; ++q) wr[q] = w1[(size_t)k * HF + tid + 256 * q];
#pragma unroll
        for (int n = 0; n < TN2; ++n) {
            float xv = xs[n][k];
#pragma unroll
            for (int q = 0; q < 4; ++q) h[n][q] = fmaf(xv, wr[q], h[n][q]);
        }
    }
    float b1r[4], w2r[4];
#pragma unroll
    for (int q = 0; q < 4; ++q) { b1r[q] = b1[tid + 256 * q]; w2r[q] = w2[tid + 256 * q]; }
    for (int n = 0; n < TN2; ++n) {
        float s = 0.f;
#pragma unroll
        for (int q = 0; q < 4; ++q) {
            float hv = h[n][q] + b1r[q];
            s += (hv > 0.f ? hv : 0.f) * w2r[q];
        }
        part[tid] = s;
        __syncthreads();
        for (int off = 128; off > 0; off >>= 1) {
            if (tid < off) part[tid] += part[tid + off];
            __syncthreads();
        }
        if (tid == 0) zout[n0 + n] = part[0];
        __syncthreads();
    }
}

// -- Stage 2 (v12): bucket-sort by max-rank endpoint + SPECULATIVE SWAR replay
// Order-equivalence with reference (see v8 note): rank order (encf(f), tid)
// refines f-order + elder tie-break; every edge in bucket r has the rank-r
// vertex as its max endpoint, so within a bucket all merges share death
// fvr[r] and the dying-root set is order-independent => bucket sort by rhi.
// Replay (v12): v11's 235 cyc/edge chain was update->readlane->decode->update
// (one wave, all latency exposed). v12 pre-reads edge e+2's raw roots TWO
// iterations early; a missed update only transforms roots young->elder, so
// the stale read is repaired EXACTLY by two conditional selects against the
// pending (young,elder) pairs of edges e-2, e-1. Loop-carried chains shrink
// to {SWAR update ~7 VALU} || {fixup ~5 SALU}; readlanes sit in the
// 2-iteration slack. Sentinel INF edges (lo=hi=255) and identity fixup pairs
// (255,255) are natural no-ops -> no prologue/tail special cases.
__global__ __launch_bounds__(256) void k_pers(
    const int* __restrict__ edges, const float* __restrict__ zbuf,
    const float* __restrict__ b2, float* __restrict__ dout /* [2][NTOT] */)
{
    const int bid = blockIdx.x;
    const int g = bid >> 1, sgn = bid & 1;
    const int tid = threadIdx.x;

    __shared__ float fv[NODES];
    __shared__ unsigned long long vkey[NODES];
    __shared__ int order_[NODES], rank_[NODES];
    __shared__ float fvr[NODES];
    __shared__ unsigned eks[EDGES];     // packed (rhi<<8)|rlo; INF self-loop
    __shared__ unsigned srt[EDGES];     // bucket-sorted by rhi + INF sentinel
    __shared__ int ofs[NODES];          // histogram -> bucket offsets -> ends
    __shared__ int par[NODES], dr[NODES], cmaxr[NODES];

    float z0 = zbuf[g * NODES + tid];
    float f0 = 1.f / (1.f + expf(-(z0 + b2[0])));
    fv[tid] = sgn ? -f0 : f0;
    unsigned long long myk = ((unsigned long long)encf(fv[tid]) << 32) | (unsigned)tid;
    vkey[tid] = myk;
    dr[tid] = 0; cmaxr[tid] = 0; ofs[tid] = 0;
#pragma unroll
    for (int q = 0; q < 4; ++q) srt[tid + q * 256] = INF32;
    __syncthreads();

    // counting rank (keys unique): rank = #{j : key[j] < mine}
    int rk = 0;
#pragma unroll 8
    for (int j = 0; j < NODES; ++j) rk += (vkey[j] < myk) ? 1 : 0;
    order_[rk] = tid;
    rank_[tid] = rk;
    fvr[rk] = fv[tid];
    __syncthreads();

    // edge keys in rank domain + histogram over rhi buckets
#pragma unroll
    for (int q = 0; q < 4; ++q) {
        int e = tid + q * 256;
        int u = edges[2 * (g * EDGES + e)]     - g * NODES;
        int v = edges[2 * (g * EDGES + e) + 1] - g * NODES;
        unsigned k = INF32;
        if (u != v) {
            int ra = rank_[u], rb = rank_[v];
            int rlo = ra < rb ? ra : rb, rhi = ra < rb ? rb : ra;
            k = ((unsigned)rhi << 8) | (unsigned)rlo;
            atomicAdd(&ofs[rhi], 1);
        }
        eks[e] = k;
    }
    __syncthreads();

    // exclusive prefix over the 256 bins, wave 0 only
    if (tid < 64) {
        int h0 = ofs[tid * 4], h1 = ofs[tid * 4 + 1];
        int h2 = ofs[tid * 4 + 2], h3 = ofs[tid * 4 + 3];
        int lsum = h0 + h1 + h2 + h3;
        int s = lsum;
#pragma unroll
        for (int d = 1; d < 64; d <<= 1) {
            int t = __shfl_up(s, d, 64);
            if (tid >= d) s += t;
        }
        int base = s - lsum;
        ofs[tid * 4]     = base;
        ofs[tid * 4 + 1] = base + h0;
        ofs[tid * 4 + 2] = base + h0 + h1;
        ofs[tid * 4 + 3] = base + h0 + h1 + h2;
    }
    __syncthreads();

    // scatter into buckets (within-bucket order arbitrary — see note)
#pragma unroll
    for (int q = 0; q < 4; ++q) {
        unsigned k = eks[tid + q * 256];
        if (k != INF32) {
            int pos = atomicAdd(&ofs[k >> 8], 1);
            srt[pos] = k;
        }
    }
    __syncthreads();

    // speculative branchless SWAR replay on wave 0
    if (tid < 64) {
        const int ln = tid;
        unsigned rpack = (unsigned)ln * 0x01010101u + 0xC0804000u;
        unsigned dpack = 0u;
        int nm = 0;
        const int ne = ofs[NODES - 1];   // end of last bucket = #valid edges
        unsigned kbA = srt[ln];          // current 64-edge block
        unsigned kbB = srt[64 + ln];     // next block (srt INF-padded to 1024)
        // pipeline prologue: raw roots for edges 0,1 (no prior updates)
        unsigned k_e  = (unsigned)__builtin_amdgcn_readlane((int)kbA, 0);
        unsigned k_e1 = (unsigned)__builtin_amdgcn_readlane((int)kbA, 1);
        unsigned ra_e  = (unsigned)__builtin_amdgcn_readlane((int)rpack, (int)(k_e  & 63u));
        unsigned rb_e  = (unsigned)__builtin_amdgcn_readlane((int)rpack, (int)((k_e  >> 8) & 63u));
        unsigned ra_e1 = (unsigned)__builtin_amdgcn_readlane((int)rpack, (int)(k_e1 & 63u));
        unsigned rb_e1 = (unsigned)__builtin_amdgcn_readlane((int)rpack, (int)((k_e1 >> 8) & 63u));
        int yA = 255, eA = 255;          // pending update of edge e-2 (identity)
        int yB = 255, eB = 255;          // pending update of edge e-1 (identity)
        for (int blk = 0; blk < EDGES / 64; ++blk) {
            if (blk * 64 >= ne || nm >= NODES - 1) break;
#pragma unroll 1
            for (int sl = 0; sl < 64; ++sl) {
                // -- pre-read edge e+2 (sees updates <= e-1; misses e, e+1) --
                const int l2 = (sl + 2) & 63;
                const unsigned k2a = (unsigned)__builtin_amdgcn_readlane((int)kbA, l2);
                const unsigned k2b = (unsigned)__builtin_amdgcn_readlane((int)kbB, l2);
                const unsigned k2 = (sl < 62) ? k2a : k2b;
                const unsigned ra2 = (unsigned)__builtin_amdgcn_readlane((int)rpack, (int)(k2 & 63u));
                const unsigned rb2 = (unsigned)__builtin_amdgcn_readlane((int)rpack, (int)((k2 >> 8) & 63u));
                // -- process edge e: extract + exact two-step fixup ---------
                const int lo = (int)(k_e & 255u), hi = (int)((k_e >> 8) & 255u);
                int ca = (int)((ra_e >> (((unsigned)lo >> 6) << 3)) & 255u);
                int cb = (int)((rb_e >> (((unsigned)hi >> 6) << 3)) & 255u);
                ca = (ca == yA) ? eA : ca;  cb = (cb == yA) ? eA : cb;
                ca = (ca == yB) ? eB : ca;  cb = (cb == yB) ? eB : cb;
                const int elder = ca < cb ? ca : cb;
                const int young = ca > cb ? ca : cb;  // == elder when no merge
                // -- SWAR root update (bytes == young -> elder) -------------
                const unsigned y4 = (unsigned)young * 0x01010101u;
                const unsigned d4 = (unsigned)(young ^ elder) * 0x01010101u;
                const unsigned mm = rpack ^ y4;
                const unsigned ww = (mm | 0x80808080u) - 0x01010101u;
                const unsigned zm = ~(ww | mm) & 0x80808080u;
                rpack ^= d4 & ((zm >> 7) * 255u);
                // -- death write (owner lane of root `young`) ---------------
                const int merged = (ca != cb) ? 1 : 0;
                const int ysel = merged ? (young & 63) : 64;   // 64: no lane
                const unsigned shy = (unsigned)((young >> 6) << 3);
                const unsigned nd = (dpack & ~(255u << shy)) | ((unsigned)hi << shy);
                dpack = (ln == ysel) ? nd : dpack;
                nm += merged;
                // -- rotate pipeline ----------------------------------------
                yA = yB; eA = eB; yB = young; eB = elder;
                k_e = k_e1; ra_e = ra_e1; rb_e = rb_e1;
                k_e1 = k2; ra_e1 = ra2; rb_e1 = rb2;
            }
            kbA = kbB;
            int nb = blk + 2; nb = nb > (EDGES / 64 - 1) ? (EDGES / 64 - 1) : nb;
            kbB = srt[nb * 64 + ln];
        }
        par[ln]       = (int)(rpack & 255u);
        par[ln + 64]  = (int)((rpack >> 8) & 255u);
        par[ln + 128] = (int)((rpack >> 16) & 255u);
        par[ln + 192] = (int)(rpack >> 24);
        dr[ln]        = (int)(dpack & 255u);
        dr[ln + 64]   = (int)((dpack >> 8) & 255u);
        dr[ln + 128]  = (int)((dpack >> 16) & 255u);
        dr[ln + 192]  = (int)(dpack >> 24);
    }
    __syncthreads();

    // component max (extended persistence); par[tid] is already the root
    const int r = par[tid];
    atomicMax(&cmaxr[r], tid);
    __syncthreads();

    const int db = dr[tid];
    float dv = (db != 0) ? fvr[db] : fvr[cmaxr[r]];
    dout[sgn * NTOT + g * NODES + order_[tid]] = dv;
}

// ------- Stage 3: per-pair MLPs + segment sum + linear head (fused) -------
__global__ __launch_bounds__(256) void k_head(
    const float* __restrict__ zbuf, const float* __restrict__ b2,
    const float* __restrict__ dbuf,
    const float* __restrict__ wp0, const float* __restrict__ bp0,
    const float* __restrict__ wp1, const float* __restrict__ bp1,
    const float* __restrict__ wh, const float* __restrict__ bh,
    float* __restrict__ out)
{
    const int g = blockIdx.x, tid = threadIdx.x;
    __shared__ float lf[NODES], l0[NODES], l1[NODES];
    __shared__ float sp0[NODES], sp1[NODES];
    lf[tid] = 1.f / (1.f + expf(-(zbuf[g * NODES + tid] + b2[0])));
    l0[tid] = dbuf[g * NODES + tid];
    l1[tid] = dbuf[NTOT + g * NODES + tid];
    __syncthreads();
    const float w00 = wp0[tid], w01 = wp0[HP + tid], bb0 = bp0[tid];
    const float w10 = wp1[tid], w11 = wp1[HP + tid], bb1 = bp1[tid];
    float s0 = 0.f, s1 = 0.f;
    for (int n = 0; n < NODES; ++n) {
        float f = lf[n], d0 = l0[n], d1 = l1[n];
        float a0 = fmaf(f, w00, fmaf(d0, w01, bb0));      // h0 = (f, d_sub)
        float a1 = fmaf(-d1, w10, fmaf(f, w11, bb1));     // h1 = (-d_sup, f)
        s0 += a0 > 0.f ? a0 : 0.f;
        s1 += a1 > 0.f ? a1 : 0.f;
    }
    sp0[tid] = s0; sp1[tid] = s1;
    __syncthreads();
    if (tid < NC) {
        float acc = bh[tid];
        for (int j = 0; j < HP; ++j)
            acc += sp0[j] * wh[j * NC + tid] + sp1[j] * wh[(HP + j) * NC + tid];
        out[g * NC + tid] = acc;   // f32 output (reference dtype)
    }
}

extern "C" void kernel_launch(void* const* d_in, const int* in_sizes, int n_in,
                              void* d_out, int out_size, void* d_ws, size_t ws_size,
                              hipStream_t stream)
{
    const float* x   = (const float*)d_in[0];
    const int*   edg = (const int*)d_in[1];
    const float* w1  = (const float*)d_in[3];
    const float* b1  = (const float*)d_in[4];
    const float* w2  = (const float*)d_in[5];
    const float* b2  = (const float*)d_in[6];
    const float* wp0 = (const float*)d_in[7];
    const float* bp0 = (const float*)d_in[8];
    const float* wp1 = (const float*)d_in[9];
    const float* bp1 = (const float*)d_in[10];
    const float* wh  = (const float*)d_in[11];
    const float* bh  = (const float*)d_in[12];

    float* zbuf = (float*)d_ws;                       // [NTOT] f32 (pre-sigmoid)
    float* dbuf = zbuf + NTOT;                        // [2][NTOT] f32
    unsigned short* w1f = (unsigned short*)(dbuf + 2 * NTOT);  // 1 MB bf16

    const size_t WS_REQ = (size_t)3 * NTOT * 4 + (size_t)HF * DF * 2 + 256;

    if (ws_size >= WS_REQ) {
        k_cvt_frag<<<256, 256, 0, stream>>>(w1, w1f);
        k_fil_mfma<<<256, 256, 0, stream>>>(x, w1f, b1, w2, zbuf);
    } else {
        k_fil     <<<NTOT / TN2, 256, 0, stream>>>(x, w1, b1, w2, zbuf);
    }
    k_pers<<<NUM_GRAPHS * 2, 256, 0, stream>>>(edg, zbuf, b2, dbuf);
    k_head<<<NUM_GRAPHS, 256, 0, stream>>>(zbuf, b2, dbuf, wp0, bp0, wp1, bp1,
                                           wh, bh, (float*)d_out);
}

// Round 8
// 223.541 us; speedup vs baseline: 1.4220x; 1.4220x over previous
//
#include <hip/hip_runtime.h>
#include <hip/hip_bf16.h>

#define NUM_GRAPHS 64
#define NODES 256
#define EDGES 1024
#define NTOT (NUM_GRAPHS * NODES) /* 16384 */
#define DF 512
#define HF 1024
#define HP 256
#define NC 10
#define INF32 0xFFFFFFFFu

typedef short bf16x8 __attribute__((ext_vector_type(8)));
typedef float f32x4 __attribute__((ext_vector_type(4)));

__device__ __forceinline__ unsigned short bf16r(float f) {
    __hip_bfloat16 h = __float2bfloat16(f);
    return *(unsigned short*)&h;
}
// monotone order-preserving encode for fp32 (bijection, works for +/-)
__device__ __forceinline__ unsigned encf(float x) {
    union { float f; unsigned u; } c; c.f = x;
    return (c.u & 0x80000000u) ? ~c.u : (c.u | 0x80000000u);
}

// ---- w1 (f32 [k][j]) -> w1f bf16, LANE-ORDERED MFMA B-fragment layout ----
// Element addr: ((cg*16 + t)*64 + lane)*8 shorts, lane = quad*16 + n16;
// lane holds B[k = t*32 + quad*8 + j][col = cg*16 + n16].
__global__ __launch_bounds__(256) void k_cvt_frag(
    const float* __restrict__ w1, unsigned short* __restrict__ w1f)
{
    __shared__ float ls[128 * 16];   // [kk][c], 8 KB
    const int tid = threadIdx.x;
    const int cg = blockIdx.x >> 2, kq = blockIdx.x & 3;
    const int c = tid & 15, kr = tid >> 4;
#pragma unroll
    for (int it = 0; it < 8; ++it) {
        int kk = it * 16 + kr;
        ls[kk * 16 + c] = w1[(size_t)(kq * 128 + kk) * HF + cg * 16 + c];
    }
    __syncthreads();
    const int tt = tid >> 6, n16 = tid & 15, q = (tid >> 4) & 3;
    unsigned short v[8];
#pragma unroll
    for (int j = 0; j < 8; ++j)
        v[j] = bf16r(ls[(tt * 32 + q * 8 + j) * 16 + n16]);
    size_t off = ((size_t)(cg * 16 + kq * 4 + tt) * 64 + (q * 16 + n16)) * 8;
#pragma unroll
    for (int j = 0; j < 8; ++j) w1f[off + j] = v[j];
}

// ------- Stage 1 (MFMA v6): zbuf = relu(x@W1+b1)@w2 (pre-b2/sigmoid) ------
// 256 blocks x 64 rows x 256 thr. Wave wv: rows r0+(wv&1)*32..+32 (A in 128
// VGPR), cols half (wv>>1)*512..+512 (32 cgs). B quad-buffered 4x16 KB LDS;
// per-step staging of one cg per half. 4 independent MFMA chains. Partial
// sums joined across halves via LDS. Math identical to v5b (K split 2).
__global__ __launch_bounds__(256, 1) void k_fil_mfma(
    const float* __restrict__ x, const unsigned short* __restrict__ w1f,
    const float* __restrict__ b1, const float* __restrict__ w2,
    float* __restrict__ zbuf)
{
    __shared__ unsigned short Bbuf[4 * 16 * 512];  // 4 x 16 KB
    __shared__ float zpart[4][32];
    const int tid = threadIdx.x;
    const int lane = tid & 63;
    const int wv = tid >> 6;            // 0..3
    const int l15 = lane & 15, quad = lane >> 4;
    const int half = wv >> 1;           // column half (32 cgs)
    const int rt = wv & 1;              // row 32-tile
    const int r0 = blockIdx.x * 64;
    const int rowA = r0 + rt * 32 + l15;
    const int rowB = rowA + 16;

    // A fragments for 32 rows: two 16-row tiles, f32 -> bf16 in regs
    bf16x8 A0[16], A1[16];
#pragma unroll
    for (int t = 0; t < 16; ++t) {
        const float* s0 = x + (size_t)rowA * DF + t * 32 + quad * 8;
        const float* s1 = x + (size_t)rowB * DF + t * 32 + quad * 8;
        float4 a = *(const float4*)s0, b = *(const float4*)(s0 + 4);
        float4 c = *(const float4*)s1, d = *(const float4*)(s1 + 4);
        A0[t][0]=(short)bf16r(a.x); A0[t][1]=(short)bf16r(a.y);
        A0[t][2]=(short)bf16r(a.z); A0[t][3]=(short)bf16r(a.w);
        A0[t][4]=(short)bf16r(b.x); A0[t][5]=(short)bf16r(b.y);
        A0[t][6]=(short)bf16r(b.z); A0[t][7]=(short)bf16r(b.w);
        A1[t][0]=(short)bf16r(c.x); A1[t][1]=(short)bf16r(c.y);
        A1[t][2]=(short)bf16r(c.z); A1[t][3]=(short)bf16r(c.w);
        A1[t][4]=(short)bf16r(d.x); A1[t][5]=(short)bf16r(d.y);
        A1[t][6]=(short)bf16r(d.z); A1[t][7]=(short)bf16r(d.w);
    }

    // staging: threads 0-127 stage half 0, 128-255 stage half 1 (8 uint4 ea)
    const int t128 = tid & 127;
    const int sh = tid >> 7;
    uint4 pf[8];
    {
        const uint4* s = (const uint4*)(w1f + (size_t)(sh * 32) * 8192);
#pragma unroll
        for (int j = 0; j < 8; ++j) pf[j] = s[t128 + j * 128];
        uint4* d = (uint4*)Bbuf + (sh * 2 + 0) * 1024;
#pragma unroll
        for (int j = 0; j < 8; ++j) d[t128 + j * 128] = pf[j];
    }
    __syncthreads();

    float s_[2][4] = {{0,0,0,0},{0,0,0,0}};

    for (int i = 0; i < 32; ++i) {
        const int par = i & 1;
        if (i < 31) {
            const uint4* s = (const uint4*)(w1f + (size_t)(sh * 32 + i + 1) * 8192);
#pragma unroll
            for (int j = 0; j < 8; ++j) pf[j] = s[t128 + j * 128];
        }
        const unsigned short* bb = Bbuf + (half * 2 + par) * 8192 + lane * 8;
        f32x4 a00={0,0,0,0}, a01={0,0,0,0}, a10={0,0,0,0}, a11={0,0,0,0};
#pragma unroll
        for (int t = 0; t < 8; ++t) {
            bf16x8 Bf0 = *(const bf16x8*)(bb + t * 512);
            bf16x8 Bf1 = *(const bf16x8*)(bb + (t + 8) * 512);
            a00 = __builtin_amdgcn_mfma_f32_16x16x32_bf16(A0[t], Bf0, a00, 0, 0, 0);
            a10 = __builtin_amdgcn_mfma_f32_16x16x32_bf16(A1[t], Bf0, a10, 0, 0, 0);
            a01 = __builtin_amdgcn_mfma_f32_16x16x32_bf16(A0[t + 8], Bf1, a01, 0, 0, 0);
            a11 = __builtin_amdgcn_mfma_f32_16x16x32_bf16(A1[t + 8], Bf1, a11, 0, 0, 0);
        }
        const int col = (half * 32 + i) * 16 + l15;
        const float b1c = b1[col], w2c = w2[col];
#pragma unroll
        for (int r = 0; r < 4; ++r) {
            float h0 = (a00[r] + a01[r]) + b1c; h0 = h0 > 0.f ? h0 : 0.f;
            s_[0][r] = fmaf(h0, w2c, s_[0][r]);
            float h1 = (a10[r] + a11[r]) + b1c; h1 = h1 > 0.f ? h1 : 0.f;
            s_[1][r] = fmaf(h1, w2c, s_[1][r]);
        }
        if (i < 31) {
            uint4* d = (uint4*)Bbuf + (sh * 2 + (par ^ 1)) * 1024;
#pragma unroll
            for (int j = 0; j < 8; ++j) d[t128 + j * 128] = pf[j];
        }
        __syncthreads();
    }

    // reduce over 16 col-lanes; publish per-wave partials; join halves
#pragma unroll
    for (int sub = 0; sub < 2; ++sub)
#pragma unroll
        for (int r = 0; r < 4; ++r) {
            float v = s_[sub][r];
            v += __shfl_xor(v, 1, 16);
            v += __shfl_xor(v, 2, 16);
            v += __shfl_xor(v, 4, 16);
            v += __shfl_xor(v, 8, 16);
            if (l15 == 0) zpart[wv][sub * 16 + quad * 4 + r] = v;
        }
    __syncthreads();
    if (tid < 64) {
        int rrt = tid >> 5, idx = tid & 31;
        zbuf[r0 + tid] = zpart[rrt][idx] + zpart[rrt + 2][idx];
    }
}

// ---------------- Stage 1 legacy (fp32 VALU) — ws_size fallback -----------
#define TN2 16
__global__ __launch_bounds__(256) void k_fil(
    const float* __restrict__ x, const float* __restrict__ w1,
    const float* __restrict__ b1, const float* __restrict__ w2,
    float* __restrict__ zout)
{
    __shared__ float xs[TN2][DF];
    __shared__ float part[256];
    const int tid = threadIdx.x;
    const int n0 = blockIdx.x * TN2;
    for (int c = tid; c < TN2 * DF / 4; c += 256) {
        int n = c >> 7, k4 = (c & 127) << 2;
        *(float4*)&xs[n][k4] = *(const float4*)(x + (size_t)(n0 + n) * DF + k4);
    }
    __syncthreads();
    float h[TN2][4];
#pragma unroll
    for (int n = 0; n < TN2; ++n)
#pragma unroll
        for (int q = 0; q < 4; ++q) h[n][q] = 0.f;
    for (int k = 0; k < DF; ++k) {
        float wr[4];
#pragma unroll
        for (int q = 0; q < 4; ++q) wr[q] = w1[(size_t)k * HF + tid + 256 * q];
#pragma unroll
        for (int n = 0; n < TN2; ++n) {
            float xv = xs[n][k];
#pragma unroll
            for (int q = 0; q < 4; ++q) h[n][q] = fmaf(xv, wr[q], h[n][q]);
        }
    }
    float b1r[4], w2r[4];
#pragma unroll
    for (int q = 0; q < 4; ++q) { b1r[q] = b1[tid + 256 * q]; w2r[q] = w2[tid + 256 * q]; }
    for (int n = 0; n < TN2; ++n) {
        float s = 0.f;
#pragma unroll
        for (int q = 0; q < 4; ++q) {
            float hv = h[n][q] + b1r[q];
            s += (hv > 0.f ? hv : 0.f) * w2r[q];
        }
        part[tid] = s;
        __syncthreads();
        for (int off = 128; off > 0; off >>= 1) {
            if (tid < off) part[tid] += part[tid + off];
            __syncthreads();
        }
        if (tid == 0) zout[n0 + n] = part[0];
        __syncthreads();
    }
}

// ------------- Stage 2 (v7r): Boruvka MST filter + wave-parallel replay ---
// Restored from the best-measured variant (71.6us k_pers, 222.6us total).
// Bucket-sort-family variants (v8-v12) all hit the single-wave serial
// regime: cycles/edge ~ 9 x instrs/edge over ALL 1024 edges -> 100-230us.
// Boruvka filters the serial set to <=255 MST edges using 4-wave parallel
// rounds; only change vs v7: pointer-jumping does 4 jumps per barrier round
// (reads are all pre-write state -> identical semantics, half the barriers).
__global__ __launch_bounds__(256) void k_pers(
    const int* __restrict__ edges, const float* __restrict__ zbuf,
    const float* __restrict__ b2, float* __restrict__ dout /* [2][NTOT] */)
{
    const int bid = blockIdx.x;
    const int g = bid >> 1, sgn = bid & 1;
    const int tid = threadIdx.x;

    __shared__ float fv[NODES];
    __shared__ unsigned long long vkey[NODES];
    __shared__ int order_[NODES], rank_[NODES];
    __shared__ float fvr[NODES];
    __shared__ unsigned eks[EDGES];
    __shared__ int comp[NODES];
    __shared__ unsigned minE[NODES];
    __shared__ int nxt[NODES], par2[NODES];
    __shared__ unsigned char mstflag[EDGES];
    __shared__ int cnt, chg;
    __shared__ unsigned mstK[NODES], srt[NODES];
    __shared__ int par[NODES], dr[NODES], cmaxr[NODES];

    float z0 = zbuf[g * NODES + tid];
    float f0 = 1.f / (1.f + expf(-(z0 + b2[0])));
    fv[tid] = sgn ? -f0 : f0;
    unsigned long long myk = ((unsigned long long)encf(fv[tid]) << 32) | (unsigned)tid;
    vkey[tid] = myk;
    srt[tid] = INF32; dr[tid] = -1; cmaxr[tid] = 0; par[tid] = tid;
    __syncthreads();

    // counting rank (keys unique): rank = #{j : key[j] < mine}
    int rk = 0;
#pragma unroll 8
    for (int j = 0; j < NODES; ++j) rk += (vkey[j] < myk) ? 1 : 0;
    order_[rk] = tid;
    rank_[tid] = rk;
    fvr[rk] = fv[tid];
    comp[tid] = tid;
    __syncthreads();

    // edge keys in rank domain; self-loops -> INF
#pragma unroll
    for (int q = 0; q < 4; ++q) {
        int e = tid + q * 256;
        int u = edges[2 * (g * EDGES + e)]     - g * NODES;
        int v = edges[2 * (g * EDGES + e) + 1] - g * NODES;
        if (u == v) { eks[e] = INF32; }
        else {
            int ra = rank_[u], rb = rank_[v];
            int rlo = ra < rb ? ra : rb, rhi = ra < rb ? rb : ra;
            eks[e] = ((unsigned)rhi << 18) | ((unsigned)e << 8) | (unsigned)rlo;
        }
        mstflag[e] = 0;
    }
    __syncthreads();

    // Boruvka with early exit, intra-comp pruning, convergence jumping
    for (int round = 0; round < 8; ++round) {
        minE[tid] = INF32;
        if (tid == 0) chg = 0;
        __syncthreads();
#pragma unroll
        for (int q = 0; q < 4; ++q) {
            int e = tid + q * 256;
            unsigned k = eks[e];
            if (k != INF32) {
                int rlo = (int)(k & 255u), rhi = (int)(k >> 18);
                int cu = comp[rlo], cv = comp[rhi];
                if (cu != cv) {
                    atomicMin(&minE[cu], k);
                    atomicMin(&minE[cv], k);
                } else if (!mstflag[e]) {
                    eks[e] = INF32;   // prune: never merges again
                }
            }
        }
        __syncthreads();
        {
            unsigned mk = minE[tid];
            int o = tid;
            if (mk != INF32) {
                int rlo = (int)(mk & 255u), rhi = (int)(mk >> 18);
                int cu = comp[rlo], cv = comp[rhi];
                o = (cu == tid) ? cv : cu;
                mstflag[(mk >> 8) & 0x3FFu] = 1;
                chg = 1;
            }
            nxt[tid] = o;
        }
        __syncthreads();
        if (!chg) break;
        {
            int o = nxt[tid];
            int p = o;
            if (nxt[o] == tid && tid < o) p = tid;
            par2[tid] = p;
        }
        __syncthreads();
        for (;;) {
            int p = par2[par2[tid]];
            p = par2[par2[p]];                 // 4 jumps per barrier round
            int done = __syncthreads_and(p == par2[tid]);
            if (done) break;
            par2[tid] = p;
            __syncthreads();
        }
        comp[tid] = par2[comp[tid]];
        __syncthreads();
    }

    // collect MST edges (<=255)
    if (tid == 0) cnt = 0;
    __syncthreads();
#pragma unroll
    for (int q = 0; q < 4; ++q) {
        int e = tid + q * 256;
        if (mstflag[e]) {
            int p = atomicAdd(&cnt, 1);
            mstK[p] = eks[e];
        }
    }
    __syncthreads();
    if (tid >= cnt) mstK[tid] = INF32;
    __syncthreads();

    // counting sort of MST keys (unique among valid)
    unsigned myk2 = mstK[tid];
    if (myk2 != INF32) {
        int pos = 0;
#pragma unroll 8
        for (int j = 0; j < NODES; ++j) pos += (mstK[j] < myk2) ? 1 : 0;
        srt[pos] = myk2;
    }
    __syncthreads();

    // wave-parallel Kruskal replay on wave 0 (rank domain; root = comp min).
    // Invariant: after each merge, r{0..3} hold exact roots for all 256
    // vertices (full compression) -> find is one readlane, union is 4
    // cndmasks. All lane indices are wave-uniform (derived from readlane'd
    // key), so no bpermute and no barriers on the critical chain.
    if (tid < 64) {
        const int ln = tid;
        int r0 = ln, r1 = 64 + ln, r2 = 128 + ln, r3 = 192 + ln;
        int d0 = -1, d1 = -1, d2 = -1, d3 = -1;
        int sv0 = (int)srt[ln], sv1 = (int)srt[ln + 64];
        int sv2 = (int)srt[ln + 128], sv3 = (int)srt[ln + 192];
        const int n = cnt;
        for (int blk = 0; blk < 4; ++blk) {
            const int base = blk << 6;
            if (base >= n) break;
            int lim = n - base; if (lim > 64) lim = 64;
            const int svb = blk == 0 ? sv0 : blk == 1 ? sv1 : blk == 2 ? sv2 : sv3;
            for (int sl = 0; sl < lim; ++sl) {
                unsigned k = (unsigned)__builtin_amdgcn_readlane(svb, sl);
                const int rlo = (int)(k & 255u);
                const int rhi = (int)(k >> 18);
                const int jl = rlo >> 6, jh = rhi >> 6;
                const int cl = jl == 0 ? r0 : jl == 1 ? r1 : jl == 2 ? r2 : r3;
                const int a = __builtin_amdgcn_readlane(cl, rlo & 63);
                const int ch = jh == 0 ? r0 : jh == 1 ? r1 : jh == 2 ? r2 : r3;
                const int b = __builtin_amdgcn_readlane(ch, rhi & 63);
                if (a != b) {   // always true for MST edges; kept for safety
                    const int elder = a < b ? a : b, young = a < b ? b : a;
                    r0 = (r0 == young) ? elder : r0;
                    r1 = (r1 == young) ? elder : r1;
                    r2 = (r2 == young) ? elder : r2;
                    r3 = (r3 == young) ? elder : r3;
                    const int jy = young >> 6;
                    const bool own = (ln == (young & 63));
                    if (jy == 0)      { if (own) d0 = rhi; }
                    else if (jy == 1) { if (own) d1 = rhi; }
                    else if (jy == 2) { if (own) d2 = rhi; }
                    else              { if (own) d3 = rhi; }
                }
            }
        }
        par[ln] = r0; par[ln + 64] = r1; par[ln + 128] = r2; par[ln + 192] = r3;
        dr[ln] = d0; dr[ln + 64] = d1; dr[ln + 128] = d2; dr[ln + 192] = d3;
    }
    __syncthreads();

    // component max (extended persistence); par[tid] is already the root
    const int r = par[tid];
    atomicMax(&cmaxr[r], tid);
    __syncthreads();

    float dv = (dr[tid] >= 0) ? fvr[dr[tid]] : fvr[cmaxr[r]];
    dout[sgn * NTOT + g * NODES + order_[tid]] = dv;
}

// ------- Stage 3: per-pair MLPs + segment sum + linear head (fused) -------
__global__ __launch_bounds__(256) void k_head(
    const float* __restrict__ zbuf, const float* __restrict__ b2,
    const float* __restrict__ dbuf,
    const float* __restrict__ wp0, const float* __restrict__ bp0,
    const float* __restrict__ wp1, const float* __restrict__ bp1,
    const float* __restrict__ wh, const float* __restrict__ bh,
    float* __restrict__ out)
{
    const int g = blockIdx.x, tid = threadIdx.x;
    __shared__ float lf[NODES], l0[NODES], l1[NODES];
    __shared__ float sp0[NODES], sp1[NODES];
    lf[tid] = 1.f / (1.f + expf(-(zbuf[g * NODES + tid] + b2[0])));
    l0[tid] = dbuf[g * NODES + tid];
    l1[tid] = dbuf[NTOT + g * NODES + tid];
    __syncthreads();
    const float w00 = wp0[tid], w01 = wp0[HP + tid], bb0 = bp0[tid];
    const float w10 = wp1[tid], w11 = wp1[HP + tid], bb1 = bp1[tid];
    float s0 = 0.f, s1 = 0.f;
    for (int n = 0; n < NODES; ++n) {
        float f = lf[n], d0 = l0[n], d1 = l1[n];
        float a0 = fmaf(f, w00, fmaf(d0, w01, bb0));      // h0 = (f, d_sub)
        float a1 = fmaf(-d1, w10, fmaf(f, w11, bb1));     // h1 = (-d_sup, f)
        s0 += a0 > 0.f ? a0 : 0.f;
        s1 += a1 > 0.f ? a1 : 0.f;
    }
    sp0[tid] = s0; sp1[tid] = s1;
    __syncthreads();
    if (tid < NC) {
        float acc = bh[tid];
        for (int j = 0; j < HP; ++j)
            acc += sp0[j] * wh[j * NC + tid] + sp1[j] * wh[(HP + j) * NC + tid];
        out[g * NC + tid] = acc;   // f32 output (reference dtype)
    }
}

extern "C" void kernel_launch(void* const* d_in, const int* in_sizes, int n_in,
                              void* d_out, int out_size, void* d_ws, size_t ws_size,
                              hipStream_t stream)
{
    const float* x   = (const float*)d_in[0];
    const int*   edg = (const int*)d_in[1];
    const float* w1  = (const float*)d_in[3];
    const float* b1  = (const float*)d_in[4];
    const float* w2  = (const float*)d_in[5];
    const float* b2  = (const float*)d_in[6];
    const float* wp0 = (const float*)d_in[7];
    const float* bp0 = (const float*)d_in[8];
    const float* wp1 = (const float*)d_in[9];
    const float* bp1 = (const float*)d_in[10];
    const float* wh  = (const float*)d_in[11];
    const float* bh  = (const float*)d_in[12];

    float* zbuf = (float*)d_ws;                       // [NTOT] f32 (pre-sigmoid)
    float* dbuf = zbuf + NTOT;                        // [2][NTOT] f32
    unsigned short* w1f = (unsigned short*)(dbuf + 2 * NTOT);  // 1 MB bf16

    const size_t WS_REQ = (size_t)3 * NTOT * 4 + (size_t)HF * DF * 2 + 256;

    if (ws_size >= WS_REQ) {
        k_cvt_frag<<<256, 256, 0, stream>>>(w1, w1f);
        k_fil_mfma<<<256, 256, 0, stream>>>(x, w1f, b1, w2, zbuf);
    } else {
        k_fil     <<<NTOT / TN2, 256, 0, stream>>>(x, w1, b1, w2, zbuf);
    }
    k_pers<<<NUM_GRAPHS * 2, 256, 0, stream>>>(edg, zbuf, b2, dbuf);
    k_head<<<NUM_GRAPHS, 256, 0, stream>>>(zbuf, b2, dbuf, wp0, bp0, wp1, bp1,
                                           wh, bh, (float*)d_out);
}

// Round 9
// 209.836 us; speedup vs baseline: 1.5149x; 1.0653x over previous
//
#include <hip/hip_runtime.h>
#include <hip/hip_bf16.h>

#define NUM_GRAPHS 64
#define NODES 256
#define EDGES 1024
#define NTOT (NUM_GRAPHS * NODES) /* 16384 */
#define DF 512
#define HF 1024
#define HP 256
#define NC 10
#define INF32 0xFFFFFFFFu

typedef short bf16x8 __attribute__((ext_vector_type(8)));
typedef float f32x4 __attribute__((ext_vector_type(4)));

__device__ __forceinline__ unsigned short bf16r(float f) {
    __hip_bfloat16 h = __float2bfloat16(f);
    return *(unsigned short*)&h;
}
// monotone order-preserving encode for fp32 (bijection, works for +/-)
__device__ __forceinline__ unsigned encf(float x) {
    union { float f; unsigned u; } c; c.f = x;
    return (c.u & 0x80000000u) ? ~c.u : (c.u | 0x80000000u);
}

// ---- w1 (f32 [k][j]) -> w1f bf16, LANE-ORDERED MFMA B-fragment layout ----
// Element addr: ((cg*16 + t)*64 + lane)*8 shorts, lane = quad*16 + n16;
// lane holds B[k = t*32 + quad*8 + j][col = cg*16 + n16].
__global__ __launch_bounds__(256) void k_cvt_frag(
    const float* __restrict__ w1, unsigned short* __restrict__ w1f)
{
    __shared__ float ls[128 * 16];   // [kk][c], 8 KB
    const int tid = threadIdx.x;
    const int cg = blockIdx.x >> 2, kq = blockIdx.x & 3;
    const int c = tid & 15, kr = tid >> 4;
#pragma unroll
    for (int it = 0; it < 8; ++it) {
        int kk = it * 16 + kr;
        ls[kk * 16 + c] = w1[(size_t)(kq * 128 + kk) * HF + cg * 16 + c];
    }
    __syncthreads();
    const int tt = tid >> 6, n16 = tid & 15, q = (tid >> 4) & 3;
    unsigned short v[8];
#pragma unroll
    for (int j = 0; j < 8; ++j)
        v[j] = bf16r(ls[(tt * 32 + q * 8 + j) * 16 + n16]);
    size_t off = ((size_t)(cg * 16 + kq * 4 + tt) * 64 + (q * 16 + n16)) * 8;
#pragma unroll
    for (int j = 0; j < 8; ++j) w1f[off + j] = v[j];
}

// ------- Stage 1 (MFMA v6): zbuf = relu(x@W1+b1)@w2 (pre-b2/sigmoid) ------
// 256 blocks x 64 rows x 256 thr. Wave wv: rows r0+(wv&1)*32..+32 (A in 128
// VGPR), cols half (wv>>1)*512..+512 (32 cgs). B quad-buffered 4x16 KB LDS;
// per-step staging of one cg per half. 4 independent MFMA chains. Partial
// sums joined across halves via LDS. Math identical to v5b (K split 2).
__global__ __launch_bounds__(256, 1) void k_fil_mfma(
    const float* __restrict__ x, const unsigned short* __restrict__ w1f,
    const float* __restrict__ b1, const float* __restrict__ w2,
    float* __restrict__ zbuf)
{
    __shared__ unsigned short Bbuf[4 * 16 * 512];  // 4 x 16 KB
    __shared__ float zpart[4][32];
    const int tid = threadIdx.x;
    const int lane = tid & 63;
    const int wv = tid >> 6;            // 0..3
    const int l15 = lane & 15, quad = lane >> 4;
    const int half = wv >> 1;           // column half (32 cgs)
    const int rt = wv & 1;              // row 32-tile
    const int r0 = blockIdx.x * 64;
    const int rowA = r0 + rt * 32 + l15;
    const int rowB = rowA + 16;

    // A fragments for 32 rows: two 16-row tiles, f32 -> bf16 in regs
    bf16x8 A0[16], A1[16];
#pragma unroll
    for (int t = 0; t < 16; ++t) {
        const float* s0 = x + (size_t)rowA * DF + t * 32 + quad * 8;
        const float* s1 = x + (size_t)rowB * DF + t * 32 + quad * 8;
        float4 a = *(const float4*)s0, b = *(const float4*)(s0 + 4);
        float4 c = *(const float4*)s1, d = *(const float4*)(s1 + 4);
        A0[t][0]=(short)bf16r(a.x); A0[t][1]=(short)bf16r(a.y);
        A0[t][2]=(short)bf16r(a.z); A0[t][3]=(short)bf16r(a.w);
        A0[t][4]=(short)bf16r(b.x); A0[t][5]=(short)bf16r(b.y);
        A0[t][6]=(short)bf16r(b.z); A0[t][7]=(short)bf16r(b.w);
        A1[t][0]=(short)bf16r(c.x); A1[t][1]=(short)bf16r(c.y);
        A1[t][2]=(short)bf16r(c.z); A1[t][3]=(short)bf16r(c.w);
        A1[t][4]=(short)bf16r(d.x); A1[t][5]=(short)bf16r(d.y);
        A1[t][6]=(short)bf16r(d.z); A1[t][7]=(short)bf16r(d.w);
    }

    // staging: threads 0-127 stage half 0, 128-255 stage half 1 (8 uint4 ea)
    const int t128 = tid & 127;
    const int sh = tid >> 7;
    uint4 pf[8];
    {
        const uint4* s = (const uint4*)(w1f + (size_t)(sh * 32) * 8192);
#pragma unroll
        for (int j = 0; j < 8; ++j) pf[j] = s[t128 + j * 128];
        uint4* d = (uint4*)Bbuf + (sh * 2 + 0) * 1024;
#pragma unroll
        for (int j = 0; j < 8; ++j) d[t128 + j * 128] = pf[j];
    }
    __syncthreads();

    float s_[2][4] = {{0,0,0,0},{0,0,0,0}};

    for (int i = 0; i < 32; ++i) {
        const int par = i & 1;
        if (i < 31) {
            const uint4* s = (const uint4*)(w1f + (size_t)(sh * 32 + i + 1) * 8192);
#pragma unroll
            for (int j = 0; j < 8; ++j) pf[j] = s[t128 + j * 128];
        }
        const unsigned short* bb = Bbuf + (half * 2 + par) * 8192 + lane * 8;
        f32x4 a00={0,0,0,0}, a01={0,0,0,0}, a10={0,0,0,0}, a11={0,0,0,0};
#pragma unroll
        for (int t = 0; t < 8; ++t) {
            bf16x8 Bf0 = *(const bf16x8*)(bb + t * 512);
            bf16x8 Bf1 = *(const bf16x8*)(bb + (t + 8) * 512);
            a00 = __builtin_amdgcn_mfma_f32_16x16x32_bf16(A0[t], Bf0, a00, 0, 0, 0);
            a10 = __builtin_amdgcn_mfma_f32_16x16x32_bf16(A1[t], Bf0, a10, 0, 0, 0);
            a01 = __builtin_amdgcn_mfma_f32_16x16x32_bf16(A0[t + 8], Bf1, a01, 0, 0, 0);
            a11 = __builtin_amdgcn_mfma_f32_16x16x32_bf16(A1[t + 8], Bf1, a11, 0, 0, 0);
        }
        const int col = (half * 32 + i) * 16 + l15;
        const float b1c = b1[col], w2c = w2[col];
#pragma unroll
        for (int r = 0; r < 4; ++r) {
            float h0 = (a00[r] + a01[r]) + b1c; h0 = h0 > 0.f ? h0 : 0.f;
            s_[0][r] = fmaf(h0, w2c, s_[0][r]);
            float h1 = (a10[r] + a11[r]) + b1c; h1 = h1 > 0.f ? h1 : 0.f;
            s_[1][r] = fmaf(h1, w2c, s_[1][r]);
        }
        if (i < 31) {
            uint4* d = (uint4*)Bbuf + (sh * 2 + (par ^ 1)) * 1024;
#pragma unroll
            for (int j = 0; j < 8; ++j) d[t128 + j * 128] = pf[j];
        }
        __syncthreads();
    }

    // reduce over 16 col-lanes; publish per-wave partials; join halves
#pragma unroll
    for (int sub = 0; sub < 2; ++sub)
#pragma unroll
        for (int r = 0; r < 4; ++r) {
            float v = s_[sub][r];
            v += __shfl_xor(v, 1, 16);
            v += __shfl_xor(v, 2, 16);
            v += __shfl_xor(v, 4, 16);
            v += __shfl_xor(v, 8, 16);
            if (l15 == 0) zpart[wv][sub * 16 + quad * 4 + r] = v;
        }
    __syncthreads();
    if (tid < 64) {
        int rrt = tid >> 5, idx = tid & 31;
        zbuf[r0 + tid] = zpart[rrt][idx] + zpart[rrt + 2][idx];
    }
}

// ---------------- Stage 1 legacy (fp32 VALU) — ws_size fallback -----------
#define TN2 16
__global__ __launch_bounds__(256) void k_fil(
    const float* __restrict__ x, const float* __restrict__ w1,
    const float* __restrict__ b1, const float* __restrict__ w2,
    float* __restrict__ zout)
{
    __shared__ float xs[TN2][DF];
    __shared__ float part[256];
    const int tid = threadIdx.x;
    const int n0 = blockIdx.x * TN2;
    for (int c = tid; c < TN2 * DF / 4; c += 256) {
        int n = c >> 7, k4 = (c & 127) << 2;
        *(float4*)&xs[n][k4] = *(const float4*)(x + (size_t)(n0 + n) * DF + k4);
    }
    __syncthreads();
    float h[TN2][4];
#pragma unroll
    for (int n = 0; n < TN2; ++n)
#pragma unroll
        for (int q = 0; q < 4; ++q) h[n][q] = 0.f;
    for (int k = 0; k < DF; ++k) {
        float wr[4];
#pragma unroll
        for (int q = 0; q < 4; ++q) wr[q] = w1[(size_t)k * HF + tid + 256 * q];
#pragma unroll
        for (int n = 0; n < TN2; ++n) {
            float xv = xs[n][k];
#pragma unroll
            for (int q = 0; q < 4; ++q) h[n][q] = fmaf(xv, wr[q], h[n][q]);
        }
    }
    float b1r[4], w2r[4];
#pragma unroll
    for (int q = 0; q < 4; ++q) { b1r[q] = b1[tid + 256 * q]; w2r[q] = w2[tid + 256 * q]; }
    for (int n = 0; n < TN2; ++n) {
        float s = 0.f;
#pragma unroll
        for (int q = 0; q < 4; ++q) {
            float hv = h[n][q] + b1r[q];
            s += (hv > 0.f ? hv : 0.f) * w2r[q];
        }
        part[tid] = s;
        __syncthreads();
        for (int off = 128; off > 0; off >>= 1) {
            if (tid < off) part[tid] += part[tid + off];
            __syncthreads();
        }
        if (tid == 0) zout[n0 + n] = part[0];
        __syncthreads();
    }
}

// ----- Stage 2 (v13): v7 Boruvka+replay at 512 threads (2 waves/SIMD) -----
// v7's 4-wave block = 1 wave/SIMD: every phase pays full dependent latency
// (~6-9 cyc/instr, m114 regime). 512 threads = 2 waves/SIMD overlap ->
// effective latency of all parallel phases ~halves. Changes vs v7:
//  * rank + MST-sort counting loops split: thread (v, half) counts 128 keys,
//    combine via rkp[] partials (one extra barrier, half the loop length).
//  * edge phases: 2 edges/thread (was 4).
//  * pointer jumping: duplicated on v=tid&255 by both halves (benign
//    same-value race) so all 512 threads participate in __syncthreads_and.
//  * 256-wide phases guarded tid<256; replay unchanged (wave 0).
__global__ __launch_bounds__(512) void k_pers(
    const int* __restrict__ edges, const float* __restrict__ zbuf,
    const float* __restrict__ b2, float* __restrict__ dout /* [2][NTOT] */)
{
    const int bid = blockIdx.x;
    const int g = bid >> 1, sgn = bid & 1;
    const int tid = threadIdx.x;        // 0..511
    const int v = tid & 255, vh = tid >> 8;

    __shared__ float fv[NODES];
    __shared__ unsigned long long vkey[NODES];
    __shared__ int order_[NODES], rank_[NODES];
    __shared__ float fvr[NODES];
    __shared__ unsigned eks[EDGES];
    __shared__ int comp[NODES];
    __shared__ unsigned minE[NODES];
    __shared__ int nxt[NODES], par2[NODES];
    __shared__ unsigned char mstflag[EDGES];
    __shared__ int cnt, chg;
    __shared__ unsigned mstK[NODES], srt[NODES];
    __shared__ int par[NODES], dr[NODES], cmaxr[NODES];
    __shared__ int rkp[512];

    if (tid < 256) {
        float z0 = zbuf[g * NODES + tid];
        float f0 = 1.f / (1.f + expf(-(z0 + b2[0])));
        fv[tid] = sgn ? -f0 : f0;
        vkey[tid] = ((unsigned long long)encf(fv[tid]) << 32) | (unsigned)tid;
        srt[tid] = INF32; dr[tid] = -1; cmaxr[tid] = 0; par[tid] = tid;
        comp[tid] = tid;
    }
    __syncthreads();

    // split counting rank: (v, vh) counts keys in [vh*128, vh*128+128)
    {
        const unsigned long long mk = vkey[v];
        const int j0 = vh << 7;
        int c = 0;
#pragma unroll 8
        for (int j = j0; j < j0 + 128; ++j) c += (vkey[j] < mk) ? 1 : 0;
        rkp[tid] = c;
    }
    __syncthreads();
    if (tid < 256) {
        int rk = rkp[tid] + rkp[tid + 256];
        order_[rk] = tid;
        rank_[tid] = rk;
        fvr[rk] = fv[tid];
    }
    __syncthreads();

    // edge keys in rank domain; self-loops -> INF (2 edges/thread)
#pragma unroll
    for (int q = 0; q < 2; ++q) {
        int e = tid + q * 512;
        int u = edges[2 * (g * EDGES + e)]     - g * NODES;
        int w = edges[2 * (g * EDGES + e) + 1] - g * NODES;
        if (u == w) { eks[e] = INF32; }
        else {
            int ra = rank_[u], rb = rank_[w];
            int rlo = ra < rb ? ra : rb, rhi = ra < rb ? rb : ra;
            eks[e] = ((unsigned)rhi << 18) | ((unsigned)e << 8) | (unsigned)rlo;
        }
        mstflag[e] = 0;
    }
    __syncthreads();

    // Boruvka with early exit, intra-comp pruning, convergence jumping
    for (int round = 0; round < 8; ++round) {
        if (tid < 256) minE[tid] = INF32;
        if (tid == 0) chg = 0;
        __syncthreads();
#pragma unroll
        for (int q = 0; q < 2; ++q) {
            int e = tid + q * 512;
            unsigned k = eks[e];
            if (k != INF32) {
                int rlo = (int)(k & 255u), rhi = (int)(k >> 18);
                int cu = comp[rlo], cv = comp[rhi];
                if (cu != cv) {
                    atomicMin(&minE[cu], k);
                    atomicMin(&minE[cv], k);
                } else if (!mstflag[e]) {
                    eks[e] = INF32;   // prune: never merges again
                }
            }
        }
        __syncthreads();
        if (tid < 256) {
            unsigned mk = minE[tid];
            int o = tid;
            if (mk != INF32) {
                int rlo = (int)(mk & 255u), rhi = (int)(mk >> 18);
                int cu = comp[rlo], cv = comp[rhi];
                o = (cu == tid) ? cv : cu;
                mstflag[(mk >> 8) & 0x3FFu] = 1;
                chg = 1;
            }
            nxt[tid] = o;
        }
        __syncthreads();
        if (!chg) break;
        if (tid < 256) {
            int o = nxt[tid];
            int p = o;
            if (nxt[o] == tid && tid < o) p = tid;
            par2[tid] = p;
        }
        __syncthreads();
        for (;;) {
            int p = par2[par2[v]];              // duplicated on both halves
            int done = __syncthreads_and(p == par2[v]);
            if (done) break;
            par2[v] = p;                        // benign same-value race
            __syncthreads();
        }
        if (tid < 256) comp[tid] = par2[comp[tid]];
        __syncthreads();
    }

    // collect MST edges (<=255)
    if (tid == 0) cnt = 0;
    __syncthreads();
#pragma unroll
    for (int q = 0; q < 2; ++q) {
        int e = tid + q * 512;
        if (mstflag[e]) {
            int p = atomicAdd(&cnt, 1);
            mstK[p] = eks[e];
        }
    }
    __syncthreads();
    if (tid < 256 && tid >= cnt) mstK[tid] = INF32;
    __syncthreads();

    // split counting sort of MST keys (unique among valid)
    {
        const unsigned m2 = mstK[v];
        const int j0 = vh << 7;
        int c = 0;
        if (m2 != INF32) {
#pragma unroll 8
            for (int j = j0; j < j0 + 128; ++j) c += (mstK[j] < m2) ? 1 : 0;
        }
        rkp[tid] = c;
    }
    __syncthreads();
    if (tid < 256) {
        unsigned m2 = mstK[tid];
        if (m2 != INF32) srt[rkp[tid] + rkp[tid + 256]] = m2;
    }
    __syncthreads();

    // wave-parallel Kruskal replay on wave 0 (rank domain; root = comp min).
    // Invariant: after each merge, r{0..3} hold exact roots for all 256
    // vertices (full compression) -> find is one readlane, union is 4
    // cndmasks. All lane indices are wave-uniform (readlane'd key).
    if (tid < 64) {
        const int ln = tid;
        int r0 = ln, r1 = 64 + ln, r2 = 128 + ln, r3 = 192 + ln;
        int d0 = -1, d1 = -1, d2 = -1, d3 = -1;
        int sv0 = (int)srt[ln], sv1 = (int)srt[ln + 64];
        int sv2 = (int)srt[ln + 128], sv3 = (int)srt[ln + 192];
        const int n = cnt;
        for (int blk = 0; blk < 4; ++blk) {
            const int base = blk << 6;
            if (base >= n) break;
            int lim = n - base; if (lim > 64) lim = 64;
            const int svb = blk == 0 ? sv0 : blk == 1 ? sv1 : blk == 2 ? sv2 : sv3;
            for (int sl = 0; sl < lim; ++sl) {
                unsigned k = (unsigned)__builtin_amdgcn_readlane(svb, sl);
                const int rlo = (int)(k & 255u);
                const int rhi = (int)(k >> 18);
                const int jl = rlo >> 6, jh = rhi >> 6;
                const int cl = jl == 0 ? r0 : jl == 1 ? r1 : jl == 2 ? r2 : r3;
                const int a = __builtin_amdgcn_readlane(cl, rlo & 63);
                const int ch = jh == 0 ? r0 : jh == 1 ? r1 : jh == 2 ? r2 : r3;
                const int b = __builtin_amdgcn_readlane(ch, rhi & 63);
                if (a != b) {   // always true for MST edges; kept for safety
                    const int elder = a < b ? a : b, young = a < b ? b : a;
                    r0 = (r0 == young) ? elder : r0;
                    r1 = (r1 == young) ? elder : r1;
                    r2 = (r2 == young) ? elder : r2;
                    r3 = (r3 == young) ? elder : r3;
                    const int jy = young >> 6;
                    const bool own = (ln == (young & 63));
                    if (jy == 0)      { if (own) d0 = rhi; }
                    else if (jy == 1) { if (own) d1 = rhi; }
                    else if (jy == 2) { if (own) d2 = rhi; }
                    else              { if (own) d3 = rhi; }
                }
            }
        }
        par[ln] = r0; par[ln + 64] = r1; par[ln + 128] = r2; par[ln + 192] = r3;
        dr[ln] = d0; dr[ln + 64] = d1; dr[ln + 128] = d2; dr[ln + 192] = d3;
    }
    __syncthreads();

    // component max (extended persistence); par[tid] is already the root
    if (tid < 256) {
        const int r = par[tid];
        atomicMax(&cmaxr[r], tid);
    }
    __syncthreads();

    if (tid < 256) {
        const int r = par[tid];
        float dv = (dr[tid] >= 0) ? fvr[dr[tid]] : fvr[cmaxr[r]];
        dout[sgn * NTOT + g * NODES + order_[tid]] = dv;
    }
}

// ------- Stage 3: per-pair MLPs + segment sum + linear head (fused) -------
// v13: final head parallelized across all 256 threads (was: 10 lanes doing
// 512 strided L2 loads each). Thread j reads contiguous wh rows j and 256+j,
// accumulates a 10-vector; shfl-reduce over the wave, join 4 waves via LDS.
__global__ __launch_bounds__(256) void k_head(
    const float* __restrict__ zbuf, const float* __restrict__ b2,
    const float* __restrict__ dbuf,
    const float* __restrict__ wp0, const float* __restrict__ bp0,
    const float* __restrict__ wp1, const float* __restrict__ bp1,
    const float* __restrict__ wh, const float* __restrict__ bh,
    float* __restrict__ out)
{
    const int g = blockIdx.x, tid = threadIdx.x;
    const int lane = tid & 63, wv = tid >> 6;
    __shared__ float lf[NODES], l0[NODES], l1[NODES];
    __shared__ float wpart[4][NC];
    lf[tid] = 1.f / (1.f + expf(-(zbuf[g * NODES + tid] + b2[0])));
    l0[tid] = dbuf[g * NODES + tid];
    l1[tid] = dbuf[NTOT + g * NODES + tid];
    __syncthreads();
    const float w00 = wp0[tid], w01 = wp0[HP + tid], bb0 = bp0[tid];
    const float w10 = wp1[tid], w11 = wp1[HP + tid], bb1 = bp1[tid];
    float s0 = 0.f, s1 = 0.f;
    for (int n = 0; n < NODES; ++n) {
        float f = lf[n], d0 = l0[n], d1 = l1[n];
        float a0 = fmaf(f, w00, fmaf(d0, w01, bb0));      // h0 = (f, d_sub)
        float a1 = fmaf(-d1, w10, fmaf(f, w11, bb1));     // h1 = (-d_sup, f)
        s0 += a0 > 0.f ? a0 : 0.f;
        s1 += a1 > 0.f ? a1 : 0.f;
    }
    // parallel head: thread tid holds pooled phi0[tid], phi1[tid]
    float pc[NC];
    const float* whr0 = wh + (size_t)tid * NC;
    const float* whr1 = wh + (size_t)(HP + tid) * NC;
#pragma unroll
    for (int c = 0; c < NC; ++c) pc[c] = s0 * whr0[c] + s1 * whr1[c];
#pragma unroll
    for (int off = 32; off > 0; off >>= 1)
#pragma unroll
        for (int c = 0; c < NC; ++c) pc[c] += __shfl_xor(pc[c], off, 64);
    if (lane == 0)
#pragma unroll
        for (int c = 0; c < NC; ++c) wpart[wv][c] = pc[c];
    __syncthreads();
    if (tid < NC)
        out[g * NC + tid] = bh[tid] + wpart[0][tid] + wpart[1][tid]
                          + wpart[2][tid] + wpart[3][tid];
}

extern "C" void kernel_launch(void* const* d_in, const int* in_sizes, int n_in,
                              void* d_out, int out_size, void* d_ws, size_t ws_size,
                              hipStream_t stream)
{
    const float* x   = (const float*)d_in[0];
    const int*   edg = (const int*)d_in[1];
    const float* w1  = (const float*)d_in[3];
    const float* b1  = (const float*)d_in[4];
    const float* w2  = (const float*)d_in[5];
    const float* b2  = (const float*)d_in[6];
    const float* wp0 = (const float*)d_in[7];
    const float* bp0 = (const float*)d_in[8];
    const float* wp1 = (const float*)d_in[9];
    const float* bp1 = (const float*)d_in[10];
    const float* wh  = (const float*)d_in[11];
    const float* bh  = (const float*)d_in[12];

    float* zbuf = (float*)d_ws;                       // [NTOT] f32 (pre-sigmoid)
    float* dbuf = zbuf + NTOT;                        // [2][NTOT] f32
    unsigned short* w1f = (unsigned short*)(dbuf + 2 * NTOT);  // 1 MB bf16

    const size_t WS_REQ = (size_t)3 * NTOT * 4 + (size_t)HF * DF * 2 + 256;

    if (ws_size >= WS_REQ) {
        k_cvt_frag<<<256, 256, 0, stream>>>(w1, w1f);
        k_fil_mfma<<<256, 256, 0, stream>>>(x, w1f, b1, w2, zbuf);
    } else {
        k_fil     <<<NTOT / TN2, 256, 0, stream>>>(x, w1, b1, w2, zbuf);
    }
    k_pers<<<NUM_GRAPHS * 2, 512, 0, stream>>>(edg, zbuf, b2, dbuf);
    k_head<<<NUM_GRAPHS, 256, 0, stream>>>(zbuf, b2, dbuf, wp0, bp0, wp1, bp1,
                                           wh, bh, (float*)d_out);
}